// Round 1
// baseline (8455.207 us; speedup 1.0000x reference)
//
#include <hip/hip_runtime.h>

#define D 128        // D_IN
#define DOUT 64
#define BN_EPS 1e-5f

// ---------------------------------------------------------------------------
// agg[dst[e]] += h[src[e]]  for all edges. 32 threads/edge, float4 gather,
// 4 scalar HW float atomics per thread (global_atomic_add_f32).
// ---------------------------------------------------------------------------
__global__ void scatter_add_kernel(const float* __restrict__ h,
                                   const int* __restrict__ ei,   // [2, E]
                                   float* __restrict__ agg,
                                   int n_edges) {
    int t = blockIdx.x * blockDim.x + threadIdx.x;
    int e = t >> 5;                    // edge id (32 threads per edge)
    if (e >= n_edges) return;
    int c = (t & 31) << 2;             // feature start 0,4,...,124
    int d_row = ei[e];                 // dst = edge_index[0]
    int s_row = ei[n_edges + e];       // src = edge_index[1]
    float4 hv = *(const float4*)(h + (size_t)s_row * D + c);
    float* ap = agg + (size_t)d_row * D + c;
    unsafeAtomicAdd(ap + 0, hv.x);
    unsafeAtomicAdd(ap + 1, hv.y);
    unsafeAtomicAdd(ap + 2, hv.z);
    unsafeAtomicAdd(ap + 3, hv.w);
}

// ---------------------------------------------------------------------------
// Per-feature sum and sum-of-squares of v = h + agg over all nodes.
// stats[0:128]=sum, stats[128:256]=sumsq. Block = 256 (= 2 rows x 128 feat).
// ---------------------------------------------------------------------------
__global__ void reduce_stats_kernel(const float* __restrict__ h,
                                    const float* __restrict__ agg,
                                    float* __restrict__ stats,
                                    int n_nodes) {
    int f   = threadIdx.x & (D - 1);
    int sub = threadIdx.x >> 7;        // 0 or 1
    float s1 = 0.f, s2 = 0.f;
    for (int r = blockIdx.x * 2 + sub; r < n_nodes; r += gridDim.x * 2) {
        size_t off = (size_t)r * D + f;
        float v = h[off] + agg[off];
        s1 += v;
        s2 += v * v;
    }
    __shared__ float ls1[256];
    __shared__ float ls2[256];
    ls1[threadIdx.x] = s1;
    ls2[threadIdx.x] = s2;
    __syncthreads();
    if (sub == 0) {
        s1 = ls1[f] + ls1[D + f];
        s2 = ls2[f] + ls2[D + f];
        unsafeAtomicAdd(&stats[f], s1);
        unsafeAtomicAdd(&stats[D + f], s2);
    }
}

// ---------------------------------------------------------------------------
// scale/shift from accumulated stats. 1 block x 128 threads.
// Note: readout term of the reference cancels exactly inside BN (constant
// per-feature across nodes), so it is omitted everywhere.
// ---------------------------------------------------------------------------
__global__ void finalize_stats_kernel(float* __restrict__ stats,
                                      const float* __restrict__ gamma,
                                      const float* __restrict__ beta,
                                      int layer, float inv_n) {
    int f = threadIdx.x;
    float mean = stats[f] * inv_n;
    float var  = stats[D + f] * inv_n - mean * mean;
    var = fmaxf(var, 0.f);
    float sc = gamma[layer * D + f] * rsqrtf(var + BN_EPS);
    stats[2 * D + f] = sc;                         // scale
    stats[3 * D + f] = beta[layer * D + f] - mean * sc;  // shift
}

// ---------------------------------------------------------------------------
// hout = relu((h + agg) * scale + shift), float4 grid-stride.
// hout may alias h (elementwise, same index) -> no __restrict__ on those.
// ---------------------------------------------------------------------------
__global__ void normalize_kernel(const float* h,
                                 const float* __restrict__ agg,
                                 const float* __restrict__ stats,
                                 float* hout,
                                 int total4) {
    int idx = blockIdx.x * blockDim.x + threadIdx.x;
    if (idx >= total4) return;
    int f4 = idx & (D / 4 - 1);
    float4 hv = ((const float4*)h)[idx];
    float4 av = ((const float4*)agg)[idx];
    float4 sc = ((const float4*)(stats + 2 * D))[f4];
    float4 sh = ((const float4*)(stats + 3 * D))[f4];
    float4 o;
    o.x = fmaxf(fmaf(hv.x + av.x, sc.x, sh.x), 0.f);
    o.y = fmaxf(fmaf(hv.y + av.y, sc.y, sh.y), 0.f);
    o.z = fmaxf(fmaf(hv.z + av.z, sc.z, sh.z), 0.f);
    o.w = fmaxf(fmaf(hv.w + av.w, sc.w, sh.w), 0.f);
    ((float4*)hout)[idx] = o;
}

// ---------------------------------------------------------------------------
// out[N,64] = h[N,128] @ W[128,64] + b. W staged in LDS (32 KB).
// Block 256 = 4 rows x 64 cols; each thread does one output element.
// ---------------------------------------------------------------------------
__global__ void head_matmul_kernel(const float* __restrict__ h,
                                   const float* __restrict__ W,
                                   const float* __restrict__ b,
                                   float* __restrict__ out,
                                   int n_nodes) {
    __shared__ float Ws[D * DOUT];
    for (int i = threadIdx.x; i < D * DOUT; i += 256) Ws[i] = W[i];
    __syncthreads();
    int col = threadIdx.x & (DOUT - 1);
    int r   = blockIdx.x * 4 + (threadIdx.x >> 6);
    if (r >= n_nodes) return;
    const float4* hr = (const float4*)(h + (size_t)r * D);
    float acc = b[col];
    #pragma unroll
    for (int k4 = 0; k4 < D / 4; ++k4) {
        float4 hv = hr[k4];
        int k = k4 * 4;
        acc = fmaf(hv.x, Ws[(k + 0) * DOUT + col], acc);
        acc = fmaf(hv.y, Ws[(k + 1) * DOUT + col], acc);
        acc = fmaf(hv.z, Ws[(k + 2) * DOUT + col], acc);
        acc = fmaf(hv.w, Ws[(k + 3) * DOUT + col], acc);
    }
    out[(size_t)r * DOUT + col] = acc;
}

extern "C" void kernel_launch(void* const* d_in, const int* in_sizes, int n_in,
                              void* d_out, int out_size, void* d_ws, size_t ws_size,
                              hipStream_t stream) {
    const float* x     = (const float*)d_in[0];
    const int*   ei    = (const int*)d_in[1];
    const float* gamma = (const float*)d_in[2];
    const float* beta  = (const float*)d_in[3];
    const float* W     = (const float*)d_in[4];
    const float* bvec  = (const float*)d_in[5];
    float* out = (float*)d_out;

    const int n_nodes = in_sizes[0] / D;     // 100000
    const int n_edges = in_sizes[1] / 2;     // 1600000

    const size_t feat_bytes = (size_t)n_nodes * D * sizeof(float);  // 51.2 MB
    float* agg   = (float*)d_ws;
    float* h_ws  = (float*)((char*)d_ws + feat_bytes);
    float* stats = (float*)((char*)d_ws + 2 * feat_bytes);          // 4*128 floats

    const int total4    = n_nodes * D / 4;
    const int scat_grid = (n_edges * 32 + 255) / 256;
    const int norm_grid = (total4 + 255) / 256;
    const float inv_n   = 1.0f / (float)n_nodes;

    const float* hcur = x;
    for (int layer = 0; layer < 3; ++layer) {
        hipMemsetAsync(agg, 0, feat_bytes, stream);
        hipMemsetAsync(stats, 0, 2 * D * sizeof(float), stream);
        scatter_add_kernel<<<scat_grid, 256, 0, stream>>>(hcur, ei, agg, n_edges);
        reduce_stats_kernel<<<512, 256, 0, stream>>>(hcur, agg, stats, n_nodes);
        finalize_stats_kernel<<<1, D, 0, stream>>>(stats, gamma, beta, layer, inv_n);
        normalize_kernel<<<norm_grid, 256, 0, stream>>>(hcur, agg, stats, h_ws, total4);
        hcur = h_ws;
    }
    head_matmul_kernel<<<(n_nodes + 3) / 4, 256, 0, stream>>>(hcur, W, bvec, out, n_nodes);
}

// Round 2
// 1487.676 us; speedup vs baseline: 5.6835x; 5.6835x over previous
//
#include <hip/hip_runtime.h>

#define D 128        // D_IN
#define DOUT 64
#define BN_EPS 1e-5f

// Workspace layout (see kernel_launch): vA, vB (51.2 MB each), src_sorted
// (6.4 MB), deg, cursor (400 KB each), stats[4][512] floats.
// stats slot layout: [0:128]=sum, [128:256]=sumsq, [256:384]=scale, [384:512]=shift.
// Slot 0 = identity (layer-0 input is raw x); slot L+1 = BN layer L.
// NOTE: the reference's graph-readout term is constant per-feature across
// nodes, so it cancels exactly inside BatchNorm -> omitted everywhere.

// ---------------------------------------------------------------------------
// deg[dst[e]]++ — int atomics over 100k counters (avg 16 hits each).
// ---------------------------------------------------------------------------
__global__ void hist_kernel(const int* __restrict__ ei, int* __restrict__ deg,
                            int n_edges) {
    for (int e = blockIdx.x * blockDim.x + threadIdx.x; e < n_edges;
         e += gridDim.x * blockDim.x)
        atomicAdd(&deg[ei[e]], 1);
}

// ---------------------------------------------------------------------------
// Exclusive prefix sum of deg -> cursor. Single block of 1024 threads.
// ---------------------------------------------------------------------------
__global__ void scan_kernel(const int* __restrict__ deg, int* __restrict__ cursor,
                            int n) {
    __shared__ int part[1024];
    int t = threadIdx.x;
    int chunk = (n + 1023) >> 10;
    int lo = t * chunk;
    int hi = min(n, lo + chunk);
    int s = 0;
    for (int i = lo; i < hi; ++i) s += deg[i];
    part[t] = s;
    __syncthreads();
    // Hillis-Steele inclusive scan
    for (int offs = 1; offs < 1024; offs <<= 1) {
        int val = (t >= offs) ? part[t - offs] : 0;
        __syncthreads();
        part[t] += val;
        __syncthreads();
    }
    int base = (t == 0) ? 0 : part[t - 1];
    for (int i = lo; i < hi; ++i) { cursor[i] = base; base += deg[i]; }
}

// ---------------------------------------------------------------------------
// Bucket-fill: src_sorted[cursor[dst]++] = src. After this kernel,
// cursor[i] == END offset of node i's bucket (start = end - deg[i]).
// ---------------------------------------------------------------------------
__global__ void fill_kernel(const int* __restrict__ ei, int* __restrict__ cursor,
                            int* __restrict__ srcs, int n_edges) {
    for (int e = blockIdx.x * blockDim.x + threadIdx.x; e < n_edges;
         e += gridDim.x * blockDim.x) {
        int d = ei[e];
        int s = ei[n_edges + e];
        int p = atomicAdd(&cursor[d], 1);
        srcs[p] = s;
    }
}

// ---------------------------------------------------------------------------
// stats init: zero everything, slot0 scale = 1 (identity pre-norm for layer 0).
// Launch <<<2, 1024>>>.
// ---------------------------------------------------------------------------
__global__ void stats_init_kernel(float* __restrict__ stats) {
    int t = blockIdx.x * blockDim.x + threadIdx.x;
    if (t < 4 * 512) {
        int slot = t >> 9, idx = t & 511;
        float v = 0.f;
        if (slot == 0 && idx >= 256 && idx < 384) v = 1.f;
        stats[t] = v;
    }
}

// ---------------------------------------------------------------------------
// Fused per-layer kernel: for each node i,
//   v[i] = norm(h[i]) + sum_{j in bucket(i)} norm(h[j])
// where norm = relu(fma(x, scale_prev, shift_prev)) (identity for layer 0).
// Also accumulates per-feature sum / sumsq of v into stats_cur.
// Block = 256 = 8 groups x 32 lanes; lane owns features [4*lane, 4*lane+4).
// Grid-stride over nodes, 8 nodes per block-iteration.
// ---------------------------------------------------------------------------
template <bool APPLY>
__global__ void agg_kernel(const float* __restrict__ h,
                           const int* __restrict__ srcs,
                           const int* __restrict__ cursor,  // end offsets
                           const int* __restrict__ deg,
                           const float* __restrict__ stats_prev,
                           float* __restrict__ stats_cur,
                           float* __restrict__ vout,
                           int n_nodes) {
    const int lane = threadIdx.x & 31;
    const int grp  = threadIdx.x >> 5;
    const int c    = lane << 2;
    float4 sc = *(const float4*)(stats_prev + 256 + c);
    float4 sh = *(const float4*)(stats_prev + 384 + c);
    float4 sum = make_float4(0.f, 0.f, 0.f, 0.f);
    float4 sq  = make_float4(0.f, 0.f, 0.f, 0.f);
    const int stride = gridDim.x * 8;
    for (int i = blockIdx.x * 8 + grp; i < n_nodes; i += stride) {
        int end = cursor[i];
        int dg  = deg[i];
        int off = end - dg;
        float4 a = *(const float4*)(h + (size_t)i * D + c);
        float4 v;
        if (APPLY) {
            v.x = fmaxf(fmaf(a.x, sc.x, sh.x), 0.f);
            v.y = fmaxf(fmaf(a.y, sc.y, sh.y), 0.f);
            v.z = fmaxf(fmaf(a.z, sc.z, sh.z), 0.f);
            v.w = fmaxf(fmaf(a.w, sc.w, sh.w), 0.f);
        } else {
            v = a;
        }
        for (int base = 0; base < dg; base += 32) {
            int rem = dg - base;
            int cnt = rem < 32 ? rem : 32;
            int sv  = (lane < cnt) ? srcs[off + base + lane] : 0;
            for (int k = 0; k < cnt; ++k) {
                int sj = __shfl(sv, k, 32);
                float4 b = *(const float4*)(h + (size_t)sj * D + c);
                if (APPLY) {
                    v.x += fmaxf(fmaf(b.x, sc.x, sh.x), 0.f);
                    v.y += fmaxf(fmaf(b.y, sc.y, sh.y), 0.f);
                    v.z += fmaxf(fmaf(b.z, sc.z, sh.z), 0.f);
                    v.w += fmaxf(fmaf(b.w, sc.w, sh.w), 0.f);
                } else {
                    v.x += b.x; v.y += b.y; v.z += b.z; v.w += b.w;
                }
            }
        }
        *(float4*)(vout + (size_t)i * D + c) = v;
        sum.x += v.x; sum.y += v.y; sum.z += v.z; sum.w += v.w;
        sq.x += v.x * v.x; sq.y += v.y * v.y; sq.z += v.z * v.z; sq.w += v.w * v.w;
    }
    // Block reduction across the 8 groups, then one atomic set per block.
    __shared__ float4 rs[8][32];
    __shared__ float4 rq[8][32];
    rs[grp][lane] = sum;
    rq[grp][lane] = sq;
    __syncthreads();
    for (int m = 4; m >= 1; m >>= 1) {
        if (grp < m) {
            float4 xa = rs[grp][lane], xb = rs[grp + m][lane];
            xa.x += xb.x; xa.y += xb.y; xa.z += xb.z; xa.w += xb.w;
            rs[grp][lane] = xa;
            float4 ya = rq[grp][lane], yb = rq[grp + m][lane];
            ya.x += yb.x; ya.y += yb.y; ya.z += yb.z; ya.w += yb.w;
            rq[grp][lane] = ya;
        }
        __syncthreads();
    }
    if (grp == 0) {
        float4 s1 = rs[0][lane];
        float4 s2 = rq[0][lane];
        unsafeAtomicAdd(&stats_cur[c + 0], s1.x);
        unsafeAtomicAdd(&stats_cur[c + 1], s1.y);
        unsafeAtomicAdd(&stats_cur[c + 2], s1.z);
        unsafeAtomicAdd(&stats_cur[c + 3], s1.w);
        unsafeAtomicAdd(&stats_cur[128 + c + 0], s2.x);
        unsafeAtomicAdd(&stats_cur[128 + c + 1], s2.y);
        unsafeAtomicAdd(&stats_cur[128 + c + 2], s2.z);
        unsafeAtomicAdd(&stats_cur[128 + c + 3], s2.w);
    }
}

// ---------------------------------------------------------------------------
// scale/shift from accumulated stats. 1 block x 128 threads.
// ---------------------------------------------------------------------------
__global__ void finalize_stats_kernel(float* __restrict__ stats_cur,
                                      const float* __restrict__ gamma,
                                      const float* __restrict__ beta,
                                      int layer, float inv_n) {
    int f = threadIdx.x;
    float mean = stats_cur[f] * inv_n;
    float var  = stats_cur[128 + f] * inv_n - mean * mean;
    var = fmaxf(var, 0.f);
    float s = gamma[layer * D + f] * rsqrtf(var + BN_EPS);
    stats_cur[256 + f] = s;
    stats_cur[384 + f] = beta[layer * D + f] - mean * s;
}

// ---------------------------------------------------------------------------
// out[N,64] = relu(norm3(v2)) @ W + b. W + scale/shift staged in LDS.
// Block 256 = 4 rows x 64 cols.
// ---------------------------------------------------------------------------
__global__ void head_kernel(const float* __restrict__ v2,
                            const float* __restrict__ stats3,
                            const float* __restrict__ W,
                            const float* __restrict__ b,
                            float* __restrict__ out, int n_nodes) {
    __shared__ float Ws[D * DOUT];
    __shared__ float scs[D];
    __shared__ float shs[D];
    for (int i = threadIdx.x; i < D * DOUT; i += 256) Ws[i] = W[i];
    if (threadIdx.x < D) {
        scs[threadIdx.x] = stats3[256 + threadIdx.x];
        shs[threadIdx.x] = stats3[384 + threadIdx.x];
    }
    __syncthreads();
    int col = threadIdx.x & (DOUT - 1);
    int r   = blockIdx.x * 4 + (threadIdx.x >> 6);
    if (r >= n_nodes) return;
    const float4* hr = (const float4*)(v2 + (size_t)r * D);
    float acc = b[col];
    #pragma unroll
    for (int k4 = 0; k4 < D / 4; ++k4) {
        float4 hv = hr[k4];
        int k = k4 * 4;
        float w0 = fmaxf(fmaf(hv.x, scs[k + 0], shs[k + 0]), 0.f);
        float w1 = fmaxf(fmaf(hv.y, scs[k + 1], shs[k + 1]), 0.f);
        float w2 = fmaxf(fmaf(hv.z, scs[k + 2], shs[k + 2]), 0.f);
        float w3 = fmaxf(fmaf(hv.w, scs[k + 3], shs[k + 3]), 0.f);
        acc = fmaf(w0, Ws[(k + 0) * DOUT + col], acc);
        acc = fmaf(w1, Ws[(k + 1) * DOUT + col], acc);
        acc = fmaf(w2, Ws[(k + 2) * DOUT + col], acc);
        acc = fmaf(w3, Ws[(k + 3) * DOUT + col], acc);
    }
    out[(size_t)r * DOUT + col] = acc;
}

extern "C" void kernel_launch(void* const* d_in, const int* in_sizes, int n_in,
                              void* d_out, int out_size, void* d_ws, size_t ws_size,
                              hipStream_t stream) {
    const float* x     = (const float*)d_in[0];
    const int*   ei    = (const int*)d_in[1];
    const float* gamma = (const float*)d_in[2];
    const float* beta  = (const float*)d_in[3];
    const float* W     = (const float*)d_in[4];
    const float* bvec  = (const float*)d_in[5];
    float* out = (float*)d_out;

    const int n_nodes = in_sizes[0] / D;     // 100000
    const int n_edges = in_sizes[1] / 2;     // 1600000

    const size_t feat_bytes = (size_t)n_nodes * D * sizeof(float);  // 51.2 MB
    char* p = (char*)d_ws;
    float* vA     = (float*)p; p += feat_bytes;
    float* vB     = (float*)p; p += feat_bytes;
    int*   srcs   = (int*)p;   p += (size_t)n_edges * sizeof(int);
    int*   deg    = (int*)p;   p += (size_t)n_nodes * sizeof(int);
    int*   cursor = (int*)p;   p += (size_t)n_nodes * sizeof(int);
    float* stats  = (float*)p; // 4 * 512 floats

    const float inv_n = 1.0f / (float)n_nodes;

    // --- CSR build (once per call; edge_index is layer-invariant) ---
    hipMemsetAsync(deg, 0, (size_t)n_nodes * sizeof(int), stream);
    stats_init_kernel<<<2, 1024, 0, stream>>>(stats);
    hist_kernel<<<1024, 256, 0, stream>>>(ei, deg, n_edges);
    scan_kernel<<<1, 1024, 0, stream>>>(deg, cursor, n_nodes);
    fill_kernel<<<1024, 256, 0, stream>>>(ei, cursor, srcs, n_edges);

    // --- 3 fused layers ---
    const float* h = x;
    float* vout = vA;
    for (int L = 0; L < 3; ++L) {
        float* scur = stats + (size_t)(L + 1) * 512;
        const float* sprev = stats + (size_t)L * 512;
        if (L == 0)
            agg_kernel<false><<<2048, 256, 0, stream>>>(h, srcs, cursor, deg,
                sprev, scur, vout, n_nodes);
        else
            agg_kernel<true><<<2048, 256, 0, stream>>>(h, srcs, cursor, deg,
                sprev, scur, vout, n_nodes);
        finalize_stats_kernel<<<1, D, 0, stream>>>(scur, gamma, beta, L, inv_n);
        h = vout;
        vout = (vout == vA) ? vB : vA;
    }

    // --- head: inline norm of layer 2 + matmul ---
    head_kernel<<<(n_nodes + 3) / 4, 256, 0, stream>>>(h, stats + 3 * 512, W,
                                                       bvec, out, n_nodes);
}

// Round 3
// 1347.814 us; speedup vs baseline: 6.2733x; 1.1038x over previous
//
#include <hip/hip_runtime.h>

#define D 128        // D_IN
#define DOUT 64
#define BN_EPS 1e-5f

// Workspace layout (see kernel_launch): vA, vB (51.2 MB each), src_sorted
// (6.4 MB), deg, cursor (400 KB each), stats[4][512] floats.
// stats slot layout: [0:128]=sum, [128:256]=sumsq, [256:384]=scale, [384:512]=shift.
// Slot 0 = identity (layer-0 input is raw x); slot L+1 = BN layer L.
// NOTE: the reference's graph-readout term is constant per-feature across
// nodes, so it cancels exactly inside BatchNorm -> omitted everywhere.

__global__ void hist_kernel(const int* __restrict__ ei, int* __restrict__ deg,
                            int n_edges) {
    for (int e = blockIdx.x * blockDim.x + threadIdx.x; e < n_edges;
         e += gridDim.x * blockDim.x)
        atomicAdd(&deg[ei[e]], 1);
}

__global__ void scan_kernel(const int* __restrict__ deg, int* __restrict__ cursor,
                            int n) {
    __shared__ int part[1024];
    int t = threadIdx.x;
    int chunk = (n + 1023) >> 10;
    int lo = t * chunk;
    int hi = min(n, lo + chunk);
    int s = 0;
    for (int i = lo; i < hi; ++i) s += deg[i];
    part[t] = s;
    __syncthreads();
    for (int offs = 1; offs < 1024; offs <<= 1) {
        int val = (t >= offs) ? part[t - offs] : 0;
        __syncthreads();
        part[t] += val;
        __syncthreads();
    }
    int base = (t == 0) ? 0 : part[t - 1];
    for (int i = lo; i < hi; ++i) { cursor[i] = base; base += deg[i]; }
}

// After fill, cursor[i] == END offset of node i's bucket.
__global__ void fill_kernel(const int* __restrict__ ei, int* __restrict__ cursor,
                            int* __restrict__ srcs, int n_edges) {
    for (int e = blockIdx.x * blockDim.x + threadIdx.x; e < n_edges;
         e += gridDim.x * blockDim.x) {
        int d = ei[e];
        int s = ei[n_edges + e];
        int p = atomicAdd(&cursor[d], 1);
        srcs[p] = s;
    }
}

__global__ void stats_init_kernel(float* __restrict__ stats) {
    int t = blockIdx.x * blockDim.x + threadIdx.x;
    if (t < 4 * 512) {
        int slot = t >> 9, idx = t & 511;
        float v = 0.f;
        if (slot == 0 && idx >= 256 && idx < 384) v = 1.f;
        stats[t] = v;
    }
}

// ---------------------------------------------------------------------------
// Fused per-layer kernel: v[i] = norm(h[i]) + sum_j norm(h[j]); accumulates
// per-feature sum/sumsq of v. norm = relu(x*scale_prev+shift_prev) (identity
// for layer 0). Block = 8 groups x 32 lanes; lane owns 4 features.
// Neighbor loop is 4-wide software-pipelined: 4 independent row loads in
// flight per chain (the R2 version had 1 -> latency-bound at 3 TB/s).
// ---------------------------------------------------------------------------
template <bool APPLY>
__global__ void agg_kernel(const float* __restrict__ h,
                           const int* __restrict__ srcs,
                           const int* __restrict__ cursor,  // end offsets
                           const int* __restrict__ deg,
                           const float* __restrict__ stats_prev,
                           float* __restrict__ stats_cur,
                           float* __restrict__ vout,
                           int n_nodes) {
    const int lane = threadIdx.x & 31;
    const int grp  = threadIdx.x >> 5;
    const int c    = lane << 2;
    const float* __restrict__ hc = h + c;   // lane-fixed column base
    float4 sc = *(const float4*)(stats_prev + 256 + c);
    float4 sh = *(const float4*)(stats_prev + 384 + c);
    float4 sum = make_float4(0.f, 0.f, 0.f, 0.f);
    float4 sq  = make_float4(0.f, 0.f, 0.f, 0.f);
    const int stride = gridDim.x * 8;

#define NORM(b) do { \
    if (APPLY) { \
        v.x += fmaxf(fmaf((b).x, sc.x, sh.x), 0.f); \
        v.y += fmaxf(fmaf((b).y, sc.y, sh.y), 0.f); \
        v.z += fmaxf(fmaf((b).z, sc.z, sh.z), 0.f); \
        v.w += fmaxf(fmaf((b).w, sc.w, sh.w), 0.f); \
    } else { \
        v.x += (b).x; v.y += (b).y; v.z += (b).z; v.w += (b).w; \
    } } while (0)

    for (int i = blockIdx.x * 8 + grp; i < n_nodes; i += stride) {
        int end = cursor[i];
        int dg  = deg[i];
        int off = end - dg;
        float4 a = *(const float4*)(hc + ((size_t)i << 7));
        float4 v;
        if (APPLY) {
            v.x = fmaxf(fmaf(a.x, sc.x, sh.x), 0.f);
            v.y = fmaxf(fmaf(a.y, sc.y, sh.y), 0.f);
            v.z = fmaxf(fmaf(a.z, sc.z, sh.z), 0.f);
            v.w = fmaxf(fmaf(a.w, sc.w, sh.w), 0.f);
        } else {
            v = a;
        }
        for (int base = 0; base < dg; base += 32) {
            int rem = dg - base;
            int cnt = rem < 32 ? rem : 32;
            int sv  = (lane < cnt) ? srcs[off + base + lane] : 0;
            int k = 0;
            for (; k + 4 <= cnt; k += 4) {
                int j0 = __shfl(sv, k + 0, 32);
                int j1 = __shfl(sv, k + 1, 32);
                int j2 = __shfl(sv, k + 2, 32);
                int j3 = __shfl(sv, k + 3, 32);
                float4 b0 = *(const float4*)(hc + ((size_t)j0 << 7));
                float4 b1 = *(const float4*)(hc + ((size_t)j1 << 7));
                float4 b2 = *(const float4*)(hc + ((size_t)j2 << 7));
                float4 b3 = *(const float4*)(hc + ((size_t)j3 << 7));
                NORM(b0); NORM(b1); NORM(b2); NORM(b3);
            }
            for (; k < cnt; ++k) {
                int j0 = __shfl(sv, k, 32);
                float4 b0 = *(const float4*)(hc + ((size_t)j0 << 7));
                NORM(b0);
            }
        }
        *(float4*)(vout + (size_t)i * D + c) = v;
        sum.x += v.x; sum.y += v.y; sum.z += v.z; sum.w += v.w;
        sq.x += v.x * v.x; sq.y += v.y * v.y; sq.z += v.z * v.z; sq.w += v.w * v.w;
    }
#undef NORM

    __shared__ float4 rs[8][32];
    __shared__ float4 rq[8][32];
    rs[grp][lane] = sum;
    rq[grp][lane] = sq;
    __syncthreads();
    for (int m = 4; m >= 1; m >>= 1) {
        if (grp < m) {
            float4 xa = rs[grp][lane], xb = rs[grp + m][lane];
            xa.x += xb.x; xa.y += xb.y; xa.z += xb.z; xa.w += xb.w;
            rs[grp][lane] = xa;
            float4 ya = rq[grp][lane], yb = rq[grp + m][lane];
            ya.x += yb.x; ya.y += yb.y; ya.z += yb.z; ya.w += yb.w;
            rq[grp][lane] = ya;
        }
        __syncthreads();
    }
    if (grp == 0) {
        float4 s1 = rs[0][lane];
        float4 s2 = rq[0][lane];
        unsafeAtomicAdd(&stats_cur[c + 0], s1.x);
        unsafeAtomicAdd(&stats_cur[c + 1], s1.y);
        unsafeAtomicAdd(&stats_cur[c + 2], s1.z);
        unsafeAtomicAdd(&stats_cur[c + 3], s1.w);
        unsafeAtomicAdd(&stats_cur[128 + c + 0], s2.x);
        unsafeAtomicAdd(&stats_cur[128 + c + 1], s2.y);
        unsafeAtomicAdd(&stats_cur[128 + c + 2], s2.z);
        unsafeAtomicAdd(&stats_cur[128 + c + 3], s2.w);
    }
}

__global__ void finalize_stats_kernel(float* __restrict__ stats_cur,
                                      const float* __restrict__ gamma,
                                      const float* __restrict__ beta,
                                      int layer, float inv_n) {
    int f = threadIdx.x;
    float mean = stats_cur[f] * inv_n;
    float var  = stats_cur[128 + f] * inv_n - mean * mean;
    var = fmaxf(var, 0.f);
    float s = gamma[layer * D + f] * rsqrtf(var + BN_EPS);
    stats_cur[256 + f] = s;
    stats_cur[384 + f] = beta[layer * D + f] - mean * s;
}

// ---------------------------------------------------------------------------
// out[N,64] = relu(norm3(v2)) @ W + b. 16 rows/block (4 rows per wave; the
// row pointer is wave-uniform so h loads are broadcast). W staged once per
// block and amortized over 16 rows (R2 staged it per 4 rows).
// ---------------------------------------------------------------------------
__global__ void head_kernel(const float* __restrict__ v2,
                            const float* __restrict__ stats3,
                            const float* __restrict__ W,
                            const float* __restrict__ b,
                            float* __restrict__ out, int n_nodes) {
    __shared__ float Ws[D * DOUT];
    __shared__ float scs[D];
    __shared__ float shs[D];
    for (int i = threadIdx.x; i < D * DOUT; i += 256) Ws[i] = W[i];
    if (threadIdx.x < D) {
        scs[threadIdx.x] = stats3[256 + threadIdx.x];
        shs[threadIdx.x] = stats3[384 + threadIdx.x];
    }
    __syncthreads();
    int col = threadIdx.x & (DOUT - 1);
    int rg  = threadIdx.x >> 6;             // wave id, 0..3
    float bb = b[col];
    int r0 = blockIdx.x * 16 + rg * 4;
    #pragma unroll
    for (int rr = 0; rr < 4; ++rr) {
        int r = r0 + rr;
        if (r >= n_nodes) return;
        const float4* hr = (const float4*)(v2 + (size_t)r * D);
        float acc = bb;
        #pragma unroll
        for (int k4 = 0; k4 < D / 4; ++k4) {
            float4 hv = hr[k4];
            int k = k4 * 4;
            float w0 = fmaxf(fmaf(hv.x, scs[k + 0], shs[k + 0]), 0.f);
            float w1 = fmaxf(fmaf(hv.y, scs[k + 1], shs[k + 1]), 0.f);
            float w2 = fmaxf(fmaf(hv.z, scs[k + 2], shs[k + 2]), 0.f);
            float w3 = fmaxf(fmaf(hv.w, scs[k + 3], shs[k + 3]), 0.f);
            acc = fmaf(w0, Ws[(k + 0) * DOUT + col], acc);
            acc = fmaf(w1, Ws[(k + 1) * DOUT + col], acc);
            acc = fmaf(w2, Ws[(k + 2) * DOUT + col], acc);
            acc = fmaf(w3, Ws[(k + 3) * DOUT + col], acc);
        }
        out[(size_t)r * DOUT + col] = acc;
    }
}

extern "C" void kernel_launch(void* const* d_in, const int* in_sizes, int n_in,
                              void* d_out, int out_size, void* d_ws, size_t ws_size,
                              hipStream_t stream) {
    const float* x     = (const float*)d_in[0];
    const int*   ei    = (const int*)d_in[1];
    const float* gamma = (const float*)d_in[2];
    const float* beta  = (const float*)d_in[3];
    const float* W     = (const float*)d_in[4];
    const float* bvec  = (const float*)d_in[5];
    float* out = (float*)d_out;

    const int n_nodes = in_sizes[0] / D;     // 100000
    const int n_edges = in_sizes[1] / 2;     // 1600000

    const size_t feat_bytes = (size_t)n_nodes * D * sizeof(float);  // 51.2 MB
    char* p = (char*)d_ws;
    float* vA     = (float*)p; p += feat_bytes;
    float* vB     = (float*)p; p += feat_bytes;
    int*   srcs   = (int*)p;   p += (size_t)n_edges * sizeof(int);
    int*   deg    = (int*)p;   p += (size_t)n_nodes * sizeof(int);
    int*   cursor = (int*)p;   p += (size_t)n_nodes * sizeof(int);
    float* stats  = (float*)p; // 4 * 512 floats

    const float inv_n = 1.0f / (float)n_nodes;

    // --- CSR build (once per call; edge_index is layer-invariant) ---
    hipMemsetAsync(deg, 0, (size_t)n_nodes * sizeof(int), stream);
    stats_init_kernel<<<2, 1024, 0, stream>>>(stats);
    hist_kernel<<<1024, 256, 0, stream>>>(ei, deg, n_edges);
    scan_kernel<<<1, 1024, 0, stream>>>(deg, cursor, n_nodes);
    fill_kernel<<<1024, 256, 0, stream>>>(ei, cursor, srcs, n_edges);

    // --- 3 fused layers ---
    const float* h = x;
    float* vout = vA;
    for (int L = 0; L < 3; ++L) {
        float* scur = stats + (size_t)(L + 1) * 512;
        const float* sprev = stats + (size_t)L * 512;
        if (L == 0)
            agg_kernel<false><<<2048, 256, 0, stream>>>(h, srcs, cursor, deg,
                sprev, scur, vout, n_nodes);
        else
            agg_kernel<true><<<2048, 256, 0, stream>>>(h, srcs, cursor, deg,
                sprev, scur, vout, n_nodes);
        finalize_stats_kernel<<<1, D, 0, stream>>>(scur, gamma, beta, L, inv_n);
        h = vout;
        vout = (vout == vA) ? vB : vA;
    }

    // --- head: inline norm of layer 2 + matmul ---
    head_kernel<<<(n_nodes + 15) / 16, 256, 0, stream>>>(h, stats + 3 * 512, W,
                                                         bvec, out, n_nodes);
}